// Round 1
// 268.166 us; speedup vs baseline: 1.0088x; 1.0088x over previous
//
#include <hip/hip_runtime.h>
#include <hip/hip_bf16.h>

// ContextualConv2d as implicit GEMM on MFMA.
// GEMM view: M = N*H*W = 131072, N = C_OUT = 256, K = CIN*9 = 1152.
// Round 6: (A) 256x256 macro-tile (BN = full C_OUT): kills the 2x A-panel
//          duplication of the nt-split and halves per-block B re-staging.
//          L2->LDS staged traffic 1.2 GB -> 0.6 GB (was the binding resource:
//          ~20 B/cyc/CU effective vs 57 B/cyc share).
//          (B) double-buffered LDS (2x(32+32) KB = 128 KB, m201 geometry) with
//          issue-early prefetch: ONE __syncthreads per K-step (was 2); the
//          vmcnt(0) drain waits on loads issued a full MFMA phase earlier.
//          (C) bijective XCD swizzle (512 blocks % 8 == 0): each XCD's 64
//          blocks share 4 n's of A + all of B in its private L2.
//          (D) zero_halo + prep_x + prep_wc merged into one dispatch.
// LDS swizzle (8-chunk): physical 16B chunk = logical ^ (row & 7) — unchanged,
// measured 0 bank conflicts.

#define NN   32
#define CIN  128
#define HH   64
#define WW   64
#define COUT 256
#define CDIM 64
#define HP   66
#define WP   66

#define XP_BYTES  ((size_t)NN*HP*WP*CIN*2)       // 35,684,352
#define WT_BYTES  ((size_t)9*COUT*CIN*2)         //    589,824
#define CTX_BYTES ((size_t)NN*COUT*4)            //     32,768
#define WS_NEEDED (XP_BYTES + WT_BYTES + CTX_BYTES)

typedef __attribute__((ext_vector_type(8))) short short8;   // 8 bf16 = 4 VGPRs
typedef __attribute__((ext_vector_type(4))) float float4v;

__device__ __forceinline__ void async16(const void* g, void* l) {
    __builtin_amdgcn_global_load_lds(
        (const __attribute__((address_space(1))) unsigned int*)g,
        (__attribute__((address_space(3))) unsigned int*)l, 16, 0, 0);
}

// ---------------- prep_all: fused zero_halo + prep_x + prep_wc ------------------
// blocks [0,2048):      prep_x   — x NCHW fp32 -> xP[n][h+1][w+1][ci] bf16
// blocks [2048,2568):   zero_halo — zero the 2.1 MB padded border of xP
// blocks [2568,3752):   prep_wc  — weight transpose + ctx GEMM
__global__ __launch_bounds__(256) void prep_all(
    const float* __restrict__ x, const float* __restrict__ c,
    const float* __restrict__ wgt, const float* __restrict__ cw,
    const float* __restrict__ bias,
    __hip_bfloat16* __restrict__ xP, __hip_bfloat16* __restrict__ wT,
    float* __restrict__ ctx)
{
    __shared__ float tile[CIN][65];
    int bid = blockIdx.x;
    int t   = threadIdx.x;

    if (bid < 2048) {                            // ---- prep_x ----
        int n = bid >> 6;
        int h = bid & 63;
        const float* xb = x + (size_t)n * CIN * HH * WW + (size_t)h * WW;

        int lane16 = t & 15, rgrp = t >> 4;      // 16 lanes x float4 = one 256B row
        #pragma unroll
        for (int i = 0; i < 8; ++i) {
            int ci = rgrp + i * 16;
            float4v v = *(const float4v*)(xb + (size_t)ci * (HH * WW) + lane16 * 4);
            int w0 = lane16 * 4;
            tile[ci][w0]     = v.x;
            tile[ci][w0 + 1] = v.y;
            tile[ci][w0 + 2] = v.z;
            tile[ci][w0 + 3] = v.w;
        }
        __syncthreads();

        int oct = t & 3, w = t >> 2;
        __hip_bfloat16* db = xP + (((size_t)n * HP + (h + 1)) * WP + (w + 1)) * CIN;
        #pragma unroll
        for (int p = 0; p < 4; ++p) {
            int ci0 = p * 32 + oct * 8;
            union { short8 v; __hip_bfloat16 b[8]; } u;
            #pragma unroll
            for (int j = 0; j < 8; ++j)
                u.b[j] = __float2bfloat16(tile[ci0 + j][w]);
            *(short8*)(db + ci0) = u.v;
        }
    } else if (bid < 2568) {                     // ---- zero_halo ----
        int g = (bid - 2048) * 256 + t;          // chunk id, 133120 total
        int n   = g / 4160;
        int rem = g - n * 4160;
        int pi  = rem >> 4;                      // halo position 0..259
        int oct = rem & 15;
        int hh, ww;
        if (pi < 132) { hh = (pi >= 66) ? 65 : 0; ww = pi % 66; }
        else { int p2 = pi - 132; ww = (p2 >= 64) ? 65 : 0; hh = 1 + (p2 & 63); }
        short8 z = {};
        *(short8*)(xP + (((size_t)n * HP + hh) * WP + ww) * CIN + oct * 8) = z;
    } else {                                     // ---- prep_wc ----
        int b2 = bid - 2568;
        if (b2 < 1152) {
            int idx = b2 * 256 + t;              // 294912
            int ci  = idx & 127;
            int co  = (idx >> 7) & 255;
            int tap = idx >> 15;
            wT[idx] = __float2bfloat16(wgt[((size_t)co * CIN + ci) * 9 + tap]);
        } else {
            int idx = (b2 - 1152) * 256 + t;     // 8192
            int co = idx & 255, n = idx >> 8;
            float a = bias[co];
            #pragma unroll 8
            for (int d = 0; d < CDIM; ++d) a += c[n * CDIM + d] * cw[co * CDIM + d];
            ctx[idx] = a;
        }
    }
}

// ---------------- main: implicit-GEMM conv, 256x256 tile, dbuf pipeline --------
// grid: 512 blocks = 512 m-tiles (256 positions = 4 h-rows of one n), BN = 256.
// 512 threads = 8 waves (2 m x 4 n); per-wave output 128 pos x 64 co.
// 18 K-steps (9 taps x 2 kb of BK=64); one barrier per step; stage(t+1) issued
// before compute(t) so the vmcnt(0) drain at the next barrier is nearly free.
__global__ __launch_bounds__(512) void conv_mfma(
    const __hip_bfloat16* __restrict__ xP,   // [32][66][66][128]
    const __hip_bfloat16* __restrict__ wT,   // [9][256][128]
    const float* __restrict__ ctx,           // [32][256]
    float* __restrict__ out)                 // [32][256][64][64]
{
    __shared__ __align__(16) short A_s[2][16384];   // 256 pos x 64 k, dbuf, 64 KB
    __shared__ __align__(16) short B_s[2][16384];   // 256 co  x 64 k, dbuf, 64 KB

    int bid = blockIdx.x;
    // XCD-bijective swizzle (512 % 8 == 0): XCD k owns logical tiles k*64..k*64+63
    int mt  = (bid & 7) * 64 + (bid >> 3);
    int n   = mt >> 4;                    // 0..31
    int h0  = (mt & 15) << 2;             // 4 h-rows per tile

    int tid  = threadIdx.x;
    int lane = tid & 63, wv = tid >> 6;
    int wm = (wv & 1) * 128;              // wave m-offset (positions)
    int wn = (wv >> 1) * 64;              // wave n-offset (co)

    // staging: per i-round (64 rows x 64 k = 8 KB), thread covers row (tid>>3),
    // physical 16B chunk (tid&7); LDS dst = tid*16B (wave-uniform base + lane*16).
    int rr  = tid >> 3;                               // row within i-round (0..63)
    int q8  = ((tid & 7) ^ (rr & 7)) << 3;            // logical source k-octet (shorts)
    int stg = tid * 8;                                // LDS dst (shorts), +i*4096
    const __hip_bfloat16* xA = xP + ((size_t)(n * HP + h0) * WP + rr) * CIN + q8;
    const __hip_bfloat16* xB = wT + (size_t)rr * CIN + q8;

    // fragment reads: logical chunk c = kk*4 + (lane>>4) of row (..+(lane&15));
    // physical = c ^ (lane&7)  (row&7 == lane&7: m/n offsets are multiples of 16)
    int l15   = lane & 15;
    int rowA  = (wm + l15) << 6;                      // shorts
    int rowB  = (wn + l15) << 6;
    int cofs0 = (((lane >> 4)    ) ^ (lane & 7)) << 3;
    int cofs1 = (((lane >> 4) + 4) ^ (lane & 7)) << 3;

    float4v acc[8][4] = {};

    // prologue: stage step 0 (tap 0 -> kh=0,kw=0; kb=0) into buffer 0
    #pragma unroll
    for (int i = 0; i < 4; ++i) {
        async16(xA + i * (WP * CIN), &A_s[0][i * 4096 + stg]);
        async16(xB + i * (64 * CIN), &B_s[0][i * 4096 + stg]);
    }

    for (int s = 0; s < 18; ++s) {
        int cur = s & 1;
        __syncthreads();   // drains vmcnt(0): buf[cur] staged, buf[cur^1] free

        if (s < 17) {                       // issue next step's stage EARLY
            int s1  = s + 1;
            int tap = s1 >> 1, kb = s1 & 1;
            int kh  = (tap * 11) >> 5;      // tap/3 for tap in 0..8
            int kw  = tap - kh * 3;
            const __hip_bfloat16* a1 = xA + (kh * WP + kw) * CIN + kb * 64;
            const __hip_bfloat16* b1 = xB + tap * (COUT * CIN) + kb * 64;
            short* Ad = A_s[cur ^ 1];
            short* Bd = B_s[cur ^ 1];
            #pragma unroll
            for (int i = 0; i < 4; ++i) {
                async16(a1 + i * (WP * CIN), Ad + i * 4096 + stg);
                async16(b1 + i * (64 * CIN), Bd + i * 4096 + stg);
            }
        }

        const short* Ab = A_s[cur];
        const short* Bb = B_s[cur];
        #pragma unroll
        for (int kk = 0; kk < 2; ++kk) {
            int cofs = kk ? cofs1 : cofs0;
            short8 aF[8], bF[4];
            #pragma unroll
            for (int mi = 0; mi < 8; ++mi)
                aF[mi] = *(const short8*)&Ab[rowA + mi * 1024 + cofs];
            #pragma unroll
            for (int ni = 0; ni < 4; ++ni)
                bF[ni] = *(const short8*)&Bb[rowB + ni * 1024 + cofs];
            #pragma unroll
            for (int mi = 0; mi < 8; ++mi)
                #pragma unroll
                for (int ni = 0; ni < 4; ++ni)
                    acc[mi][ni] = __builtin_amdgcn_mfma_f32_16x16x32_bf16(
                        aF[mi], bF[ni], acc[mi][ni], 0, 0, 0);
        }
    }

    // epilogue: += ctx, write float4 (4 consecutive w)
    #pragma unroll
    for (int ni = 0; ni < 4; ++ni) {
        int co = wn + ni * 16 + l15;
        float cv = ctx[n * COUT + co];
        float* ob = out + ((size_t)n * COUT + co) * (HH * WW);
        #pragma unroll
        for (int mi = 0; mi < 8; ++mi) {
            int rp = wm + mi * 16 + ((lane >> 4) << 2);   // row quad base
            int hh = h0 + (rp >> 6);
            int ww = rp & 63;
            float4v v = acc[mi][ni] + cv;
            *(float4v*)&ob[hh * WW + ww] = v;
        }
    }
}

// ---------------- fallback (round-2 verified) ----------------------------------
__global__ __launch_bounds__(256) void contextual_conv_f32(
    const float* __restrict__ x, const float* __restrict__ c,
    const float* __restrict__ wgt, const float* __restrict__ cw,
    const float* __restrict__ bias, float* __restrict__ out)
{
    int idx = blockIdx.x * 256 + threadIdx.x;
    int w = idx & 63, h = (idx >> 6) & 63, cb = (idx >> 12) & 63, n = idx >> 18;
    float acc[4];
    #pragma unroll
    for (int j = 0; j < 4; ++j) acc[j] = bias[cb + j * 64];
    const float* cp = c + n * CDIM;
    for (int d = 0; d < CDIM; ++d) {
        float cv = cp[d];
        #pragma unroll
        for (int j = 0; j < 4; ++j) acc[j] += cv * cw[(cb + j * 64) * CDIM + d];
    }
    const float* xn = x + (size_t)n * (CIN * HH * WW);
    for (int ci = 0; ci < CIN; ++ci) {
        const float* xc = xn + ci * (HH * WW);
        float wv[4][9];
        #pragma unroll
        for (int j = 0; j < 4; ++j) {
            const float* wp = wgt + ((cb + j * 64) * CIN + ci) * 9;
            #pragma unroll
            for (int k = 0; k < 9; ++k) wv[j][k] = wp[k];
        }
        #pragma unroll
        for (int kh = 0; kh < 3; ++kh) {
            int hh = h + kh - 1;
            if (hh < 0 || hh >= HH) continue;
            const float* xr = xc + hh * WW;
            #pragma unroll
            for (int kw = 0; kw < 3; ++kw) {
                int ww = w + kw - 1;
                if (ww < 0 || ww >= WW) continue;
                float xv = xr[ww];
                #pragma unroll
                for (int j = 0; j < 4; ++j) acc[j] += xv * wv[j][kh * 3 + kw];
            }
        }
    }
    size_t obase = (size_t)n * (COUT * HH * WW) + (size_t)h * WW + w;
    #pragma unroll
    for (int j = 0; j < 4; ++j)
        out[obase + (size_t)(cb + j * 64) * (HH * WW)] = acc[j];
}

extern "C" void kernel_launch(void* const* d_in, const int* in_sizes, int n_in,
                              void* d_out, int out_size, void* d_ws, size_t ws_size,
                              hipStream_t stream) {
    const float* x    = (const float*)d_in[0];
    const float* c    = (const float*)d_in[1];
    const float* wgt  = (const float*)d_in[2];
    const float* cw   = (const float*)d_in[3];
    const float* bias = (const float*)d_in[4];
    float* out = (float*)d_out;

    if (ws_size < WS_NEEDED) {   // workspace too small: round-2 fallback
        const int total_threads = NN * 64 * HH * WW;
        contextual_conv_f32<<<total_threads / 256, 256, 0, stream>>>(x, c, wgt, cw, bias, out);
        return;
    }

    char* ws = (char*)d_ws;
    __hip_bfloat16* xP = (__hip_bfloat16*)ws;
    __hip_bfloat16* wT = (__hip_bfloat16*)(ws + XP_BYTES);
    float*          cx = (float*)(ws + XP_BYTES + WT_BYTES);

    prep_all <<<3752, 256, 0, stream>>>(x, c, wgt, cw, bias, xP, wT, cx);
    conv_mfma<<<512, 512, 0, stream>>>(xP, wT, cx, out);
}

// Round 2
// 267.443 us; speedup vs baseline: 1.0116x; 1.0027x over previous
//
#include <hip/hip_runtime.h>
#include <hip/hip_bf16.h>

// ContextualConv2d as implicit GEMM on MFMA.
// GEMM view: M = N*H*W = 131072, N = C_OUT = 256, K = CIN*9 = 1152.
// Round 7: 8-phase / counted-vmcnt schedule (T3+T4) + setprio (T5) on the
//          round-6 256x256 geometry. Each K-tile (BK=64) = 4 quadrant-phases
//          of 16 MFMAs bracketed by raw s_barrier pairs; one half-tile staged
//          per phase; ONE s_waitcnt vmcnt(4) per K-tile (never 0 in the main
//          loop) keeps 2 half-tiles in flight across every barrier.
//          Stagger proof (2-deep buffer): A-halves of kt+1 staged at kt.q0/q1
//          into buf^1 (freed after kt-1.q2); B-halves of kt+2 staged at
//          kt.q2/q3 into buf (B of kt last READ at q1; stage issued after
//          q1's closing barrier => reads retired). vmcnt(4) at q3 completes
//          exactly through kt+1 while kt+2's B stays outstanding.
// LDS swizzle (8-chunk): physical 16B chunk = logical ^ (row & 7) — unchanged,
// measured 0 bank conflicts.

#define NN   32
#define CIN  128
#define HH   64
#define WW   64
#define COUT 256
#define CDIM 64
#define HP   66
#define WP   66

#define XP_BYTES  ((size_t)NN*HP*WP*CIN*2)       // 35,684,352
#define WT_BYTES  ((size_t)9*COUT*CIN*2)         //    589,824
#define CTX_BYTES ((size_t)NN*COUT*4)            //     32,768
#define WS_NEEDED (XP_BYTES + WT_BYTES + CTX_BYTES)

typedef __attribute__((ext_vector_type(8))) short short8;   // 8 bf16 = 4 VGPRs
typedef __attribute__((ext_vector_type(4))) float float4v;

__device__ __forceinline__ void async16(const void* g, void* l) {
    __builtin_amdgcn_global_load_lds(
        (const __attribute__((address_space(1))) unsigned int*)g,
        (__attribute__((address_space(3))) unsigned int*)l, 16, 0, 0);
}

#define BAR()      __builtin_amdgcn_s_barrier()
#define SETPRIO(x) __builtin_amdgcn_s_setprio(x)

// ---------------- prep_all: fused zero_halo + prep_x + prep_wc ------------------
// blocks [0,2048):      prep_x   — x NCHW fp32 -> xP[n][h+1][w+1][ci] bf16
// blocks [2048,2568):   zero_halo — zero the 2.1 MB padded border of xP
// blocks [2568,3752):   prep_wc  — weight transpose + ctx GEMM
__global__ __launch_bounds__(256) void prep_all(
    const float* __restrict__ x, const float* __restrict__ c,
    const float* __restrict__ wgt, const float* __restrict__ cw,
    const float* __restrict__ bias,
    __hip_bfloat16* __restrict__ xP, __hip_bfloat16* __restrict__ wT,
    float* __restrict__ ctx)
{
    __shared__ float tile[CIN][65];
    int bid = blockIdx.x;
    int t   = threadIdx.x;

    if (bid < 2048) {                            // ---- prep_x ----
        int n = bid >> 6;
        int h = bid & 63;
        const float* xb = x + (size_t)n * CIN * HH * WW + (size_t)h * WW;

        int lane16 = t & 15, rgrp = t >> 4;      // 16 lanes x float4 = one 256B row
        #pragma unroll
        for (int i = 0; i < 8; ++i) {
            int ci = rgrp + i * 16;
            float4v v = *(const float4v*)(xb + (size_t)ci * (HH * WW) + lane16 * 4);
            int w0 = lane16 * 4;
            tile[ci][w0]     = v.x;
            tile[ci][w0 + 1] = v.y;
            tile[ci][w0 + 2] = v.z;
            tile[ci][w0 + 3] = v.w;
        }
        __syncthreads();

        int oct = t & 3, w = t >> 2;
        __hip_bfloat16* db = xP + (((size_t)n * HP + (h + 1)) * WP + (w + 1)) * CIN;
        #pragma unroll
        for (int p = 0; p < 4; ++p) {
            int ci0 = p * 32 + oct * 8;
            union { short8 v; __hip_bfloat16 b[8]; } u;
            #pragma unroll
            for (int j = 0; j < 8; ++j)
                u.b[j] = __float2bfloat16(tile[ci0 + j][w]);
            *(short8*)(db + ci0) = u.v;
        }
    } else if (bid < 2568) {                     // ---- zero_halo ----
        int g = (bid - 2048) * 256 + t;          // chunk id, 133120 total
        int n   = g / 4160;
        int rem = g - n * 4160;
        int pi  = rem >> 4;                      // halo position 0..259
        int oct = rem & 15;
        int hh, ww;
        if (pi < 132) { hh = (pi >= 66) ? 65 : 0; ww = pi % 66; }
        else { int p2 = pi - 132; ww = (p2 >= 64) ? 65 : 0; hh = 1 + (p2 & 63); }
        short8 z = {};
        *(short8*)(xP + (((size_t)n * HP + hh) * WP + ww) * CIN + oct * 8) = z;
    } else {                                     // ---- prep_wc ----
        int b2 = bid - 2568;
        if (b2 < 1152) {
            int idx = b2 * 256 + t;              // 294912
            int ci  = idx & 127;
            int co  = (idx >> 7) & 255;
            int tap = idx >> 15;
            wT[idx] = __float2bfloat16(wgt[((size_t)co * CIN + ci) * 9 + tap]);
        } else {
            int idx = (b2 - 1152) * 256 + t;     // 8192
            int co = idx & 255, n = idx >> 8;
            float a = bias[co];
            #pragma unroll 8
            for (int d = 0; d < CDIM; ++d) a += c[n * CDIM + d] * cw[co * CDIM + d];
            ctx[idx] = a;
        }
    }
}

// ---------------- main: implicit-GEMM conv, 256x256 tile, 8-phase pipeline -----
// grid: 512 blocks = 512 m-tiles (256 positions = 4 h-rows of one n), BN = 256.
// 512 threads = 8 waves (2 m x 4 n); per-wave output 128 pos x 64 co.
// 18 K-tiles x 4 phases; per phase: {ds_read quadrant subtile || stage 1
// half-tile} -> barrier -> 16 MFMA (setprio 1) -> barrier. vmcnt(4) once per
// K-tile at q3 (vmcnt(0) only at kt=16, pipeline tail).
__global__ __launch_bounds__(512) void conv_mfma(
    const __hip_bfloat16* __restrict__ xP,   // [32][66][66][128]
    const __hip_bfloat16* __restrict__ wT,   // [9][256][128]
    const float* __restrict__ ctx,           // [32][256]
    float* __restrict__ out)                 // [32][256][64][64]
{
    __shared__ __align__(16) short A_s[2][16384];   // 256 pos x 64 k, dbuf, 64 KB
    __shared__ __align__(16) short B_s[2][16384];   // 256 co  x 64 k, dbuf, 64 KB

    int bid = blockIdx.x;
    // XCD-bijective swizzle (512 % 8 == 0): XCD k owns logical tiles k*64..k*64+63
    int mt  = (bid & 7) * 64 + (bid >> 3);
    int n   = mt >> 4;                    // 0..31
    int h0  = (mt & 15) << 2;             // 4 h-rows per tile

    int tid  = threadIdx.x;
    int lane = tid & 63, wv = tid >> 6;
    int wm = (wv & 1) * 128;              // wave m-offset (positions)
    int wn = (wv >> 1) * 64;              // wave n-offset (co)

    // staging: per i-round (64 rows x 64 k = 8 KB), thread covers row (tid>>3),
    // physical 16B chunk (tid&7); LDS dst = tid*16B. Half-tile h = i-rounds 2h,2h+1.
    int rr  = tid >> 3;                               // row within i-round (0..63)
    int q8  = ((tid & 7) ^ (rr & 7)) << 3;            // logical source k-octet (shorts)
    int stg = tid * 8;                                // LDS dst (shorts), +i*4096
    const __hip_bfloat16* xA = xP + ((size_t)(n * HP + h0) * WP + rr) * CIN + q8;
    const __hip_bfloat16* xB = wT + (size_t)rr * CIN + q8;

    // fragment reads: logical chunk c = kk*4 + (lane>>4) of row (..+(lane&15));
    // physical = c ^ (lane&7)  (row&7 == lane&7: m/n offsets are multiples of 16)
    int l15   = lane & 15;
    int rowA  = (wm + l15) << 6;                      // shorts
    int rowB  = (wn + l15) << 6;
    int cofs0 = (((lane >> 4)    ) ^ (lane & 7)) << 3;
    int cofs1 = (((lane >> 4) + 4) ^ (lane & 7)) << 3;

    float4v acc[8][4] = {};

    // ---- prologue: stage stream g=0..5 = kt0{B h0,h1, A h0,h1} + kt1{B h0,h1}
    #pragma unroll
    for (int i = 0; i < 4; ++i)                       // kt0 B (tap0, kb0)
        async16(xB + i * (64 * CIN), &B_s[0][i * 4096 + stg]);
    #pragma unroll
    for (int i = 0; i < 4; ++i)                       // kt0 A (tap0, kb0)
        async16(xA + i * (WP * CIN), &A_s[0][i * 4096 + stg]);
    #pragma unroll
    for (int i = 0; i < 4; ++i)                       // kt1 B (tap0, kb1)
        async16(xB + 64 + i * (64 * CIN), &B_s[1][i * 4096 + stg]);
    asm volatile("s_waitcnt vmcnt(4)" ::: "memory");  // kt0 fully landed
    BAR();

    #pragma unroll 2
    for (int kt = 0; kt < 18; ++kt) {
        int cur = kt & 1;
        const short* Ac = A_s[cur];
        const short* Bc = B_s[cur];

        // stage addresses: A of kt+1 -> buf^1;  B of kt+2 -> buf (same parity)
        int ktA = kt + 1, tapA = ktA >> 1, kbA = ktA & 1;
        int khA = (tapA * 11) >> 5, kwA = tapA - khA * 3;
        const __hip_bfloat16* aS = xA + (khA * WP + kwA) * CIN + kbA * 64;
        short* Ad = A_s[cur ^ 1];
        int ktB = kt + 2, tapB = ktB >> 1, kbB = ktB & 1;
        const __hip_bfloat16* bS = xB + (size_t)tapB * (COUT * CIN) + kbB * 64;
        short* Bd = B_s[cur];

        short8 a0[4][2], a1[4][2], b0[2][2], b1[2][2];

        // ---------------- q0: read A[0-3], B[0-1]; stage A-h0(kt+1) ----------
        #pragma unroll
        for (int mi = 0; mi < 4; ++mi) {
            a0[mi][0] = *(const short8*)&Ac[rowA + mi * 1024 + cofs0];
            a0[mi][1] = *(const short8*)&Ac[rowA + mi * 1024 + cofs1];
        }
        #pragma unroll
        for (int ni = 0; ni < 2; ++ni) {
            b0[ni][0] = *(const short8*)&Bc[rowB + ni * 1024 + cofs0];
            b0[ni][1] = *(const short8*)&Bc[rowB + ni * 1024 + cofs1];
        }
        if (ktA < 18) {
            async16(aS,                &Ad[0 * 4096 + stg]);
            async16(aS + 1 * (WP * CIN), &Ad[1 * 4096 + stg]);
        }
        BAR();
        SETPRIO(1);
        #pragma unroll
        for (int mi = 0; mi < 4; ++mi)
            #pragma unroll
            for (int ni = 0; ni < 2; ++ni) {
                acc[mi][ni] = __builtin_amdgcn_mfma_f32_16x16x32_bf16(
                    a0[mi][0], b0[ni][0], acc[mi][ni], 0, 0, 0);
                acc[mi][ni] = __builtin_amdgcn_mfma_f32_16x16x32_bf16(
                    a0[mi][1], b0[ni][1], acc[mi][ni], 0, 0, 0);
            }
        SETPRIO(0);
        BAR();

        // ---------------- q1: read B[2-3]; stage A-h1(kt+1) ------------------
        #pragma unroll
        for (int ni = 0; ni < 2; ++ni) {
            b1[ni][0] = *(const short8*)&Bc[rowB + (ni + 2) * 1024 + cofs0];
            b1[ni][1] = *(const short8*)&Bc[rowB + (ni + 2) * 1024 + cofs1];
        }
        if (ktA < 18) {
            async16(aS + 2 * (WP * CIN), &Ad[2 * 4096 + stg]);
            async16(aS + 3 * (WP * CIN), &Ad[3 * 4096 + stg]);
        }
        BAR();
        SETPRIO(1);
        #pragma unroll
        for (int mi = 0; mi < 4; ++mi)
            #pragma unroll
            for (int ni = 0; ni < 2; ++ni) {
                acc[mi][ni + 2] = __builtin_amdgcn_mfma_f32_16x16x32_bf16(
                    a0[mi][0], b1[ni][0], acc[mi][ni + 2], 0, 0, 0);
                acc[mi][ni + 2] = __builtin_amdgcn_mfma_f32_16x16x32_bf16(
                    a0[mi][1], b1[ni][1], acc[mi][ni + 2], 0, 0, 0);
            }
        SETPRIO(0);
        BAR();

        // ---------------- q2: read A[4-7]; stage B-h0(kt+2) ------------------
        #pragma unroll
        for (int mi = 0; mi < 4; ++mi) {
            a1[mi][0] = *(const short8*)&Ac[rowA + (mi + 4) * 1024 + cofs0];
            a1[mi][1] = *(const short8*)&Ac[rowA + (mi + 4) * 1024 + cofs1];
        }
        if (ktB < 18) {
            async16(bS,                  &Bd[0 * 4096 + stg]);
            async16(bS + 1 * (64 * CIN), &Bd[1 * 4096 + stg]);
        }
        BAR();
        SETPRIO(1);
        #pragma unroll
        for (int mi = 0; mi < 4; ++mi)
            #pragma unroll
            for (int ni = 0; ni < 2; ++ni) {
                acc[mi + 4][ni] = __builtin_amdgcn_mfma_f32_16x16x32_bf16(
                    a1[mi][0], b0[ni][0], acc[mi + 4][ni], 0, 0, 0);
                acc[mi + 4][ni] = __builtin_amdgcn_mfma_f32_16x16x32_bf16(
                    a1[mi][1], b0[ni][1], acc[mi + 4][ni], 0, 0, 0);
            }
        SETPRIO(0);
        BAR();

        // ---------------- q3: stage B-h1(kt+2); counted wait; MFMA -----------
        if (ktB < 18) {
            async16(bS + 2 * (64 * CIN), &Bd[2 * 4096 + stg]);
            async16(bS + 3 * (64 * CIN), &Bd[3 * 4096 + stg]);
        }
        if (kt <= 15) asm volatile("s_waitcnt vmcnt(4)" ::: "memory");
        else          asm volatile("s_waitcnt vmcnt(0)" ::: "memory");
        BAR();
        SETPRIO(1);
        #pragma unroll
        for (int mi = 0; mi < 4; ++mi)
            #pragma unroll
            for (int ni = 0; ni < 2; ++ni) {
                acc[mi + 4][ni + 2] = __builtin_amdgcn_mfma_f32_16x16x32_bf16(
                    a1[mi][0], b1[ni][0], acc[mi + 4][ni + 2], 0, 0, 0);
                acc[mi + 4][ni + 2] = __builtin_amdgcn_mfma_f32_16x16x32_bf16(
                    a1[mi][1], b1[ni][1], acc[mi + 4][ni + 2], 0, 0, 0);
            }
        SETPRIO(0);
        BAR();
    }

    // epilogue: += ctx, write float4 (4 consecutive w)
    #pragma unroll
    for (int ni = 0; ni < 4; ++ni) {
        int co = wn + ni * 16 + l15;
        float cv = ctx[n * COUT + co];
        float* ob = out + ((size_t)n * COUT + co) * (HH * WW);
        #pragma unroll
        for (int mi = 0; mi < 8; ++mi) {
            int rp = wm + mi * 16 + ((lane >> 4) << 2);   // row quad base
            int hh = h0 + (rp >> 6);
            int ww = rp & 63;
            float4v v = acc[mi][ni] + cv;
            *(float4v*)&ob[hh * WW + ww] = v;
        }
    }
}

// ---------------- fallback (round-2 verified) ----------------------------------
__global__ __launch_bounds__(256) void contextual_conv_f32(
    const float* __restrict__ x, const float* __restrict__ c,
    const float* __restrict__ wgt, const float* __restrict__ cw,
    const float* __restrict__ bias, float* __restrict__ out)
{
    int idx = blockIdx.x * 256 + threadIdx.x;
    int w = idx & 63, h = (idx >> 6) & 63, cb = (idx >> 12) & 63, n = idx >> 18;
    float acc[4];
    #pragma unroll
    for (int j = 0; j < 4; ++j) acc[j] = bias[cb + j * 64];
    const float* cp = c + n * CDIM;
    for (int d = 0; d < CDIM; ++d) {
        float cv = cp[d];
        #pragma unroll
        for (int j = 0; j < 4; ++j) acc[j] += cv * cw[(cb + j * 64) * CDIM + d];
    }
    const float* xn = x + (size_t)n * (CIN * HH * WW);
    for (int ci = 0; ci < CIN; ++ci) {
        const float* xc = xn + ci * (HH * WW);
        float wv[4][9];
        #pragma unroll
        for (int j = 0; j < 4; ++j) {
            const float* wp = wgt + ((cb + j * 64) * CIN + ci) * 9;
            #pragma unroll
            for (int k = 0; k < 9; ++k) wv[j][k] = wp[k];
        }
        #pragma unroll
        for (int kh = 0; kh < 3; ++kh) {
            int hh = h + kh - 1;
            if (hh < 0 || hh >= HH) continue;
            const float* xr = xc + hh * WW;
            #pragma unroll
            for (int kw = 0; kw < 3; ++kw) {
                int ww = w + kw - 1;
                if (ww < 0 || ww >= WW) continue;
                float xv = xr[ww];
                #pragma unroll
                for (int j = 0; j < 4; ++j) acc[j] += xv * wv[j][kh * 3 + kw];
            }
        }
    }
    size_t obase = (size_t)n * (COUT * HH * WW) + (size_t)h * WW + w;
    #pragma unroll
    for (int j = 0; j < 4; ++j)
        out[obase + (size_t)(cb + j * 64) * (HH * WW)] = acc[j];
}

extern "C" void kernel_launch(void* const* d_in, const int* in_sizes, int n_in,
                              void* d_out, int out_size, void* d_ws, size_t ws_size,
                              hipStream_t stream) {
    const float* x    = (const float*)d_in[0];
    const float* c    = (const float*)d_in[1];
    const float* wgt  = (const float*)d_in[2];
    const float* cw   = (const float*)d_in[3];
    const float* bias = (const float*)d_in[4];
    float* out = (float*)d_out;

    if (ws_size < WS_NEEDED) {   // workspace too small: round-2 fallback
        const int total_threads = NN * 64 * HH * WW;
        contextual_conv_f32<<<total_threads / 256, 256, 0, stream>>>(x, c, wgt, cw, bias, out);
        return;
    }

    char* ws = (char*)d_ws;
    __hip_bfloat16* xP = (__hip_bfloat16*)ws;
    __hip_bfloat16* wT = (__hip_bfloat16*)(ws + XP_BYTES);
    float*          cx = (float*)(ws + XP_BYTES + WT_BYTES);

    prep_all <<<3752, 256, 0, stream>>>(x, c, wgt, cw, bias, xP, wT, cx);
    conv_mfma<<<512, 512, 0, stream>>>(xP, wT, cx, out);
}